// Round 8
// baseline (331.282 us; speedup 1.0000x reference)
//
#include <hip/hip_runtime.h>

#define B_  32
#define C_  256
#define H_  56
#define W_  56
#define HW  3136      // H_*W_
#define KK  9
#define NPB 4             // planes per block
#define NPLANES (B_*C_)   // 8192
#define GRID2 (NPLANES/NPB) // 2048 = 256 CUs * 8 blocks -> co-resident by resource math
#define BPB 64            // blocks per batch (256 planes / 4)

typedef float v4f __attribute__((ext_vector_type(4)));

// ---------------------------------------------------------------------------
// Single fused kernel with PER-BATCH spin dependency (not a grid barrier).
// Grid 2048 @ 8 blocks/CU is fully co-resident (launch_bounds(256,8) =>
// VGPR<=64; LDS ~1.3KB), so all 64 blocks of a batch are always resident ->
// the spin cannot deadlock regardless of scheduling order.
// Why: pool(read-only) then dconv(read+write) serialized reach only ~3.4TB/s;
// interleaving batches' pool-reads with earlier batches' stencil-writes runs
// the HBM read and write streams CONCURRENTLY (copy-mode ~6.3TB/s ceiling).
// x re-read in the stencil hits this CU's own L1/L2 (same block fetched it
// in the pool phase -> automatic XCD affinity).
// ---------------------------------------------------------------------------
__global__ __launch_bounds__(256, 8)
void fused_kernel(const float* __restrict__ x,
                  const float* __restrict__ Wk,
                  const float* __restrict__ bk,
                  float* __restrict__ pp,      // padded pooled [2048][16]
                  int* __restrict__ bc,        // per-batch counters, 128B apart
                  float* __restrict__ out) {
    __shared__ float psh[C_];                  // this batch's pooled row
    __shared__ float wsh[NPB][12];             // taps for the block's 4 planes

    const int t    = threadIdx.x;
    const int lane = t & 63;
    const int wv   = t >> 6;
    const int g    = blockIdx.x;
    const int p0   = g * NPB;                  // planes p0..p0+3 (same batch)
    const int b    = g >> 6;                   // batch id

    // ---------------- Phase 1: pool (wave wv pools plane p0+wv) -----------
    {
        const float4* xp = (const float4*)(x + (size_t)(p0 + wv) * HW);
        float s = 0.f;
        #pragma unroll
        for (int kk = 0; kk < 12; ++kk) {              // 12*64 = 768 strips
            float4 v = xp[lane + kk * 64];
            s += (v.x + v.y) + (v.z + v.w);
        }
        if (lane < 16) {                               // remainder 768..783
            float4 v = xp[768 + lane];
            s += (v.x + v.y) + (v.z + v.w);
        }
        #pragma unroll
        for (int off = 32; off > 0; off >>= 1)
            s += __shfl_down(s, off, 64);
        if (lane == 0)
            __hip_atomic_store(&pp[(size_t)g * 16 + wv], s * (1.0f / (float)HW),
                               __ATOMIC_RELAXED, __HIP_MEMORY_SCOPE_AGENT);
    }
    __syncthreads();                                   // all 4 means stored (vmcnt drained)
    if (t == 0)
        __hip_atomic_fetch_add(&bc[b * 32], 1, __ATOMIC_ACQ_REL,
                               __HIP_MEMORY_SCOPE_AGENT);

    // ---------------- Phase 2: wait for this batch's 64 blocks ------------
    if (t == 0) {
        while (__hip_atomic_load(&bc[b * 32], __ATOMIC_ACQUIRE,
                                 __HIP_MEMORY_SCOPE_AGENT) < BPB)
            __builtin_amdgcn_s_sleep(2);
    }
    __syncthreads();

    // ---------------- Phase 3: batch pooled row -> LDS ---------------------
    {
        const int c   = t;                             // channel 0..255
        const int gp  = (b << 6) + (c >> 2);           // source block
        psh[c] = __hip_atomic_load(&pp[(size_t)gp * 16 + (c & 3)],
                                   __ATOMIC_RELAXED, __HIP_MEMORY_SCOPE_AGENT);
    }
    __syncthreads();

    // ---------------- Phase 4: kerngen for 4 planes ------------------------
    // 144 threads: tap j = t/4 (0..35) -> (plane q = j/9, tap o = j%9);
    // lane part l = t%4 covers 64 channels (16 float4), 2-shuffle reduce.
    if (t < 144) {
        const int j = t >> 2, l = t & 3;
        const int q = j / KK, o = j % KK;
        const int c = (p0 + q) & 255;
        const int og = c * KK + o;
        const float4* wr  = (const float4*)(Wk + (size_t)og * C_ + l * 64);
        const float4* pr4 = (const float4*)(psh + l * 64);
        float sv = 0.f;
        #pragma unroll 4
        for (int i = 0; i < 16; ++i) {
            float4 w = wr[i], p = pr4[i];
            sv += w.x * p.x + w.y * p.y + w.z * p.z + w.w * p.w;
        }
        sv += __shfl_down(sv, 2, 4);
        sv += __shfl_down(sv, 1, 4);
        if (l == 0)
            wsh[q][o] = fmaxf(sv + bk[og], 0.f);
    }
    __syncthreads();

    // ---------------- Phase 5: R3-verified register stencil, 4 planes ------
    const int k   = lane & 15;                         // col group
    const int gg  = lane >> 4;
    const bool ka = (k < 14);                          // cols 0..55
    const int c0  = ka ? (k << 2) : 0;                 // idle lanes clamped in-bounds
    const bool hl = (k > 0);
    const bool hr = (k < 13);

    #pragma unroll
    for (int q = 0; q < NPB; ++q) {
        const float w0 = wsh[q][0], w1 = wsh[q][1], w2 = wsh[q][2],
                    w3 = wsh[q][3], w4 = wsh[q][4], w5 = wsh[q][5],
                    w6 = wsh[q][6], w7 = wsh[q][7], w8 = wsh[q][8];
        const float* xp = x   + (size_t)(p0 + q) * HW;
        float*       op = out + (size_t)(p0 + q) * HW;

        #pragma unroll
        for (int half = 0; half < 2; ++half) {
            const int rp = half * 16 + wv * 4 + gg;    // 0..15, then 16..31
            if (rp >= 28) break;                       // wave-uniform exit (wv=3,half=1)

            const int rA = (rp == 0)  ? 0  : 2 * rp - 1;
            const int rB = (rp == 27) ? 55 : 2 * rp + 2;

            float4 A  = *(const float4*)(xp + rA * W_ + c0);
            float4 M  = *(const float4*)(xp + (2 * rp) * W_ + c0);
            float4 N  = *(const float4*)(xp + (2 * rp + 1) * W_ + c0);
            float4 Bv = *(const float4*)(xp + rB * W_ + c0);
            if (rp == 0)  { A.x = 0.f;  A.y = 0.f;  A.z = 0.f;  A.w = 0.f; }
            if (rp == 27) { Bv.x = 0.f; Bv.y = 0.f; Bv.z = 0.f; Bv.w = 0.f; }

            if (ka) {
                float Al = __shfl_up(A.w, 1, 16),  Ar = __shfl_down(A.x, 1, 16);
                float Ml = __shfl_up(M.w, 1, 16),  Mr = __shfl_down(M.x, 1, 16);
                float Nl = __shfl_up(N.w, 1, 16),  Nr = __shfl_down(N.x, 1, 16);
                float Bl = __shfl_up(Bv.w, 1, 16), Br = __shfl_down(Bv.x, 1, 16);
                Al = hl ? Al : 0.f;  Ml = hl ? Ml : 0.f;
                Nl = hl ? Nl : 0.f;  Bl = hl ? Bl : 0.f;
                Ar = hr ? Ar : 0.f;  Mr = hr ? Mr : 0.f;
                Nr = hr ? Nr : 0.f;  Br = hr ? Br : 0.f;

                v4f t0, t1;
                t0.x = w0*Al  + w1*A.x  + w2*A.y  + w3*Ml  + w4*M.x  + w5*M.y  + w6*Nl  + w7*N.x  + w8*N.y;
                t0.y = w0*A.x + w1*A.y  + w2*A.z  + w3*M.x + w4*M.y  + w5*M.z  + w6*N.x + w7*N.y  + w8*N.z;
                t0.z = w0*A.y + w1*A.z  + w2*A.w  + w3*M.y + w4*M.z  + w5*M.w  + w6*N.y + w7*N.z  + w8*N.w;
                t0.w = w0*A.z + w1*A.w  + w2*Ar   + w3*M.z + w4*M.w  + w5*Mr   + w6*N.z + w7*N.w  + w8*Nr;
                t1.x = w0*Ml  + w1*M.x  + w2*M.y  + w3*Nl  + w4*N.x  + w5*N.y  + w6*Bl  + w7*Bv.x + w8*Bv.y;
                t1.y = w0*M.x + w1*M.y  + w2*M.z  + w3*N.x + w4*N.y  + w5*N.z  + w6*Bv.x+ w7*Bv.y + w8*Bv.z;
                t1.z = w0*M.y + w1*M.z  + w2*M.w  + w3*N.y + w4*N.z  + w5*N.w  + w6*Bv.y+ w7*Bv.z + w8*Bv.w;
                t1.w = w0*M.z + w1*M.w  + w2*Mr   + w3*N.z + w4*N.w  + w5*Nr   + w6*Bv.z+ w7*Bv.w + w8*Br;

                *(v4f*)(op + (2 * rp + 0) * W_ + c0) = t0;
                *(v4f*)(op + (2 * rp + 1) * W_ + c0) = t1;
            }
        }
    }
}

extern "C" void kernel_launch(void* const* d_in, const int* in_sizes, int n_in,
                              void* d_out, int out_size, void* d_ws, size_t ws_size,
                              hipStream_t stream) {
    const float* x  = (const float*)d_in[0];   // [B,C,H,W]
    const float* Wk = (const float*)d_in[1];   // [C*K*K, C]
    const float* bk = (const float*)d_in[2];   // [C*K*K]
    float* out = (float*)d_out;                // [B,C,H,W]

    float* pp = (float*)d_ws;                        // [2048][16] floats = 128 KB
    int*   bc = (int*)((char*)d_ws + 131072);        // 32 counters, 128B apart (4 KB)

    // Zero batch counters each launch (capture-legal, tiny).
    hipMemsetAsync((char*)d_ws + 131072, 0, 32 * 32 * sizeof(int), stream);

    fused_kernel<<<dim3(GRID2), dim3(256), 0, stream>>>(x, Wk, bk, pp, bc, out);
}

// Round 9
// 207.374 us; speedup vs baseline: 1.5975x; 1.5975x over previous
//
#include <hip/hip_runtime.h>

#define B_  32
#define C_  256
#define H_  56
#define W_  56
#define HW  3136      // H_*W_
#define KK  9
#define NPLANES (B_*C_)   // 8192

typedef float v4f __attribute__((ext_vector_type(4)));

// ---------------------------------------------------------------------------
// Kernel 1: global average pool. One WAVE per (b,c) plane, 4 planes/block.
// Pure shuffle reduction; regular loads keep x resident in L3 for dconv.
// At the HBM read floor (~17 us) — unchanged (verified R0..R7).
// ---------------------------------------------------------------------------
__global__ __launch_bounds__(256) void pool_kernel(const float* __restrict__ x,
                                                   float* __restrict__ pooled) {
    const int wid  = threadIdx.x >> 6;
    const int lane = threadIdx.x & 63;
    const int plane = blockIdx.x * 4 + wid;             // 2048 blocks * 4 waves
    const float4* xp = (const float4*)(x + (size_t)plane * HW);

    float s = 0.f;
    #pragma unroll
    for (int k = 0; k < 12; ++k) {                      // 12*64 = 768 strips
        float4 v = xp[lane + k * 64];
        s += (v.x + v.y) + (v.z + v.w);
    }
    if (lane < 16) {                                    // remainder 768..783
        float4 v = xp[768 + lane];
        s += (v.x + v.y) + (v.z + v.w);
    }
    #pragma unroll
    for (int off = 32; off > 0; off >>= 1)
        s += __shfl_down(s, off, 64);
    if (lane == 0)
        pooled[plane] = s * (1.0f / (float)HW);
}

// ---------------------------------------------------------------------------
// Kernel 2: R3-verified register stencil + hoisted loads (both halves'
// 8 row-loads issued before any compute).
//   * kerngen (threads 0..143) -> 9 taps in 36B LDS, ONE barrier (verified).
//   * compiler waits vmcnt(4) before half-0 compute -> half-1's loads stay
//     in flight under half-0's compute+stores: one long stall per wave
//     instead of two, and the store stream overlaps the read stream.
//   * halos via __shfl_up/down(.,1,16) (DPP); regular stores (L2 merges).
//   * ~56 live VGPR, still within the 64-reg cap of (256,8) occupancy.
// ---------------------------------------------------------------------------
__global__ __launch_bounds__(256, 8) void dconv_kernel(const float* __restrict__ x,
                                                       const float* __restrict__ pooled,
                                                       const float* __restrict__ Wk,
                                                       const float* __restrict__ bk,
                                                       float* __restrict__ out) {
    const int plane = blockIdx.x;                       // b*C_ + c
    const int b = plane >> 8;
    const int c = plane & 255;
    __shared__ float wsh[KK];
    const int t = threadIdx.x;

    // Kernel generation: tap o = t/16, lane chunk = (t%16)*16 channels.
    if (t < 144) {
        const int o  = t >> 4;                          // 0..8
        const int ch = (t & 15) << 4;                   // 0,16,...,240
        const int og = c * KK + o;                      // global output row
        const float4* wr = (const float4*)(Wk + (size_t)og * C_ + ch);
        const float4* pr = (const float4*)(pooled + b * C_ + ch);
        float s = 0.f;
        #pragma unroll
        for (int i = 0; i < 4; ++i) {
            float4 w = wr[i];
            float4 p = pr[i];
            s += w.x * p.x + w.y * p.y + w.z * p.z + w.w * p.w;
        }
        #pragma unroll
        for (int off = 8; off > 0; off >>= 1)           // reduce 16-lane groups
            s += __shfl_down(s, off, 16);
        if ((t & 15) == 0)
            wsh[o] = fmaxf(s + bk[og], 0.f);
    }
    __syncthreads();

    const float w0 = wsh[0], w1 = wsh[1], w2 = wsh[2],
                w3 = wsh[3], w4 = wsh[4], w5 = wsh[5],
                w6 = wsh[6], w7 = wsh[7], w8 = wsh[8];

    const float* xp = x + (size_t)plane * HW;
    float* op = out + (size_t)plane * HW;

    const int lane = t & 63;
    const int k    = lane & 15;                         // column group: k*4
    const int g    = lane >> 4;                         // row-pair group in wave
    const int wv   = t >> 6;                            // wave id 0..3
    const bool ka  = (k < 14);                          // cols 0..55
    const int c0   = ka ? (k << 2) : 0;                 // clamp idle lanes in-bounds
    const bool hl  = (k > 0);                           // has in-row left neighbor
    const bool hr  = (k < 13);                          // has in-row right neighbor

    // ---- tile coordinates for both halves ----
    const int rp0 = wv * 4 + g;                         // 0..15 (always valid)
    const int rp1 = 16 + wv * 4 + g;                    // 16..31; valid if <28
    const bool v1 = (rp1 < 28);
    const int rp1c = v1 ? rp1 : 27;                     // clamp idle tiles in-bounds

    const int rA0 = (rp0 == 0)  ? 0  : 2 * rp0 - 1;
    const int rB0 = 2 * rp0 + 2;                        // rp0<=15 -> max 32, in-bounds
    const int rA1 = 2 * rp1c - 1;                       // rp1c>=16 -> >=31, in-bounds
    const int rB1 = (rp1c == 27) ? 55 : 2 * rp1c + 2;

    // ---- issue ALL 8 row loads up front ----
    float4 A0 = *(const float4*)(xp + rA0 * W_ + c0);
    float4 M0 = *(const float4*)(xp + (2 * rp0)     * W_ + c0);
    float4 N0 = *(const float4*)(xp + (2 * rp0 + 1) * W_ + c0);
    float4 B0 = *(const float4*)(xp + rB0 * W_ + c0);
    float4 A1 = *(const float4*)(xp + rA1 * W_ + c0);
    float4 M1 = *(const float4*)(xp + (2 * rp1c)     * W_ + c0);
    float4 N1 = *(const float4*)(xp + (2 * rp1c + 1) * W_ + c0);
    float4 B1 = *(const float4*)(xp + rB1 * W_ + c0);

    if (rp0 == 0)  { A0.x = 0.f; A0.y = 0.f; A0.z = 0.f; A0.w = 0.f; }   // row -1
    if (rp1c == 27){ B1.x = 0.f; B1.y = 0.f; B1.z = 0.f; B1.w = 0.f; }   // row 56

    // ---- half 0 compute + store (half-1 loads still in flight) ----
    if (ka) {
        float Al = __shfl_up(A0.w, 1, 16),  Ar = __shfl_down(A0.x, 1, 16);
        float Ml = __shfl_up(M0.w, 1, 16),  Mr = __shfl_down(M0.x, 1, 16);
        float Nl = __shfl_up(N0.w, 1, 16),  Nr = __shfl_down(N0.x, 1, 16);
        float Bl = __shfl_up(B0.w, 1, 16),  Br = __shfl_down(B0.x, 1, 16);
        Al = hl ? Al : 0.f;  Ml = hl ? Ml : 0.f;
        Nl = hl ? Nl : 0.f;  Bl = hl ? Bl : 0.f;
        Ar = hr ? Ar : 0.f;  Mr = hr ? Mr : 0.f;
        Nr = hr ? Nr : 0.f;  Br = hr ? Br : 0.f;

        v4f t0, t1;
        t0.x = w0*Al   + w1*A0.x + w2*A0.y + w3*Ml   + w4*M0.x + w5*M0.y + w6*Nl   + w7*N0.x + w8*N0.y;
        t0.y = w0*A0.x + w1*A0.y + w2*A0.z + w3*M0.x + w4*M0.y + w5*M0.z + w6*N0.x + w7*N0.y + w8*N0.z;
        t0.z = w0*A0.y + w1*A0.z + w2*A0.w + w3*M0.y + w4*M0.z + w5*M0.w + w6*N0.y + w7*N0.z + w8*N0.w;
        t0.w = w0*A0.z + w1*A0.w + w2*Ar   + w3*M0.z + w4*M0.w + w5*Mr   + w6*N0.z + w7*N0.w + w8*Nr;
        t1.x = w0*Ml   + w1*M0.x + w2*M0.y + w3*Nl   + w4*N0.x + w5*N0.y + w6*Bl   + w7*B0.x + w8*B0.y;
        t1.y = w0*M0.x + w1*M0.y + w2*M0.z + w3*N0.x + w4*N0.y + w5*N0.z + w6*B0.x + w7*B0.y + w8*B0.z;
        t1.z = w0*M0.y + w1*M0.z + w2*M0.w + w3*N0.y + w4*N0.z + w5*N0.w + w6*B0.y + w7*B0.z + w8*B0.w;
        t1.w = w0*M0.z + w1*M0.w + w2*Mr   + w3*N0.z + w4*N0.w + w5*Nr   + w6*B0.z + w7*B0.w + w8*Br;

        *(v4f*)(op + (2 * rp0 + 0) * W_ + c0) = t0;
        *(v4f*)(op + (2 * rp0 + 1) * W_ + c0) = t1;
    }

    // ---- half 1 compute + store ----
    if (ka & v1) {
        float Al = __shfl_up(A1.w, 1, 16),  Ar = __shfl_down(A1.x, 1, 16);
        float Ml = __shfl_up(M1.w, 1, 16),  Mr = __shfl_down(M1.x, 1, 16);
        float Nl = __shfl_up(N1.w, 1, 16),  Nr = __shfl_down(N1.x, 1, 16);
        float Bl = __shfl_up(B1.w, 1, 16),  Br = __shfl_down(B1.x, 1, 16);
        Al = hl ? Al : 0.f;  Ml = hl ? Ml : 0.f;
        Nl = hl ? Nl : 0.f;  Bl = hl ? Bl : 0.f;
        Ar = hr ? Ar : 0.f;  Mr = hr ? Mr : 0.f;
        Nr = hr ? Nr : 0.f;  Br = hr ? Br : 0.f;

        v4f t0, t1;
        t0.x = w0*Al   + w1*A1.x + w2*A1.y + w3*Ml   + w4*M1.x + w5*M1.y + w6*Nl   + w7*N1.x + w8*N1.y;
        t0.y = w0*A1.x + w1*A1.y + w2*A1.z + w3*M1.x + w4*M1.y + w5*M1.z + w6*N1.x + w7*N1.y + w8*N1.z;
        t0.z = w0*A1.y + w1*A1.z + w2*A1.w + w3*M1.y + w4*M1.z + w5*M1.w + w6*N1.y + w7*N1.z + w8*N1.w;
        t0.w = w0*A1.z + w1*A1.w + w2*Ar   + w3*M1.z + w4*M1.w + w5*Mr   + w6*N1.z + w7*N1.w + w8*Nr;
        t1.x = w0*Ml   + w1*M1.x + w2*M1.y + w3*Nl   + w4*N1.x + w5*N1.y + w6*Bl   + w7*B1.x + w8*B1.y;
        t1.y = w0*M1.x + w1*M1.y + w2*M1.z + w3*N1.x + w4*N1.y + w5*N1.z + w6*B1.x + w7*B1.y + w8*B1.z;
        t1.z = w0*M1.y + w1*M1.z + w2*M1.w + w3*N1.y + w4*N1.z + w5*N1.w + w6*B1.y + w7*B1.z + w8*B1.w;
        t1.w = w0*M1.z + w1*M1.w + w2*Mr   + w3*N1.z + w4*N1.w + w5*Nr   + w6*B1.z + w7*B1.w + w8*Br;

        *(v4f*)(op + (2 * rp1 + 0) * W_ + c0) = t0;
        *(v4f*)(op + (2 * rp1 + 1) * W_ + c0) = t1;
    }
}

extern "C" void kernel_launch(void* const* d_in, const int* in_sizes, int n_in,
                              void* d_out, int out_size, void* d_ws, size_t ws_size,
                              hipStream_t stream) {
    const float* x  = (const float*)d_in[0];   // [B,C,H,W]
    const float* Wk = (const float*)d_in[1];   // [C*K*K, C]
    const float* bk = (const float*)d_in[2];   // [C*K*K]
    float* out = (float*)d_out;                // [B,C,H,W]

    float* pooled = (float*)d_ws;              // B*C = 8192 floats

    pool_kernel<<<NPLANES / 4, 256, 0, stream>>>(x, pooled);
    dconv_kernel<<<NPLANES, 256, 0, stream>>>(x, pooled, Wk, bk, out);
}